// Round 3
// baseline (784.388 us; speedup 1.0000x reference)
//
#include <hip/hip_runtime.h>
#include <math.h>

#define HEIGHT 300
#define WIDTH  25
#define CH     16
#define BATCH  1024
// bits set at w = 3, 8, 12, 14, 17, 19
#define ROI_MASK 0x000A5108u

#define NCELL (BATCH * HEIGHT * WIDTH)   // 7,680,000 cells
#define N4    (NCELL * (CH / 4))         // 30,720,000 float4s

// Native clang ext_vector: required for __builtin_nontemporal_load/store
// (HIP's float4 is a class type and is rejected by the builtin).
typedef float f4_t __attribute__((ext_vector_type(4)));

// ---------------------------------------------------------------------------
// Kernel A: per-batch norms + full attention map a[b,h,w] = t̂[h]*ŝ[w] + roi[w]
// One wave (64 lanes) per batch row. amap is 30.7 MB -> L3-resident for kernel B.
// ---------------------------------------------------------------------------
__global__ void __launch_bounds__(64)
amap_kernel(const float* __restrict__ s_o,
            const float* __restrict__ t_o,
            float* __restrict__ amap) {
    __shared__ float t_lds[HEIGHT];
    __shared__ float s_lds[WIDTH];
    const int b    = blockIdx.x;
    const int lane = threadIdx.x;

    // load t row (300 = 4*64 + 44) and accumulate sum of squares
    const float* tr = t_o + b * HEIGHT;
    float tv[5];
    float acc_t = 0.f;
    #pragma unroll
    for (int k = 0; k < 5; ++k) {
        int i = lane + 64 * k;
        tv[k] = (i < HEIGHT) ? tr[i] : 0.f;
        acc_t += tv[k] * tv[k];
    }
    // load s row (25)
    float sv = (lane < WIDTH) ? s_o[b * WIDTH + lane] : 0.f;
    float acc_s = sv * sv;

    // wave-64 butterfly reductions
    #pragma unroll
    for (int off = 32; off > 0; off >>= 1) {
        acc_t += __shfl_down(acc_t, off, 64);
        acc_s += __shfl_down(acc_s, off, 64);
    }
    float sum_t = __shfl(acc_t, 0, 64);
    float sum_s = __shfl(acc_s, 0, 64);
    float inv_t = 1.0f / sqrtf(fmaxf(sum_t, 1e-12f));
    float inv_s = 1.0f / sqrtf(fmaxf(sum_s, 1e-12f));

    // stage normalized rows in LDS
    #pragma unroll
    for (int k = 0; k < 5; ++k) {
        int i = lane + 64 * k;
        if (i < HEIGHT) t_lds[i] = tv[k] * inv_t;
    }
    if (lane < WIDTH) s_lds[lane] = sv * inv_s;
    __syncthreads();

    // write a[b,h,w] (7500 floats per batch)
    float* am = amap + b * (HEIGHT * WIDTH);
    for (int idx = lane; idx < HEIGHT * WIDTH; idx += 64) {
        int h = (int)((unsigned)idx / WIDTH);   // compiler emits magic-mul
        int w = idx - h * WIDTH;
        float roi = (float)((ROI_MASK >> w) & 1u);
        am[idx] = fmaf(t_lds[h], s_lds[w], roi);
    }
}

// ---------------------------------------------------------------------------
// Kernel B: pure scaled stream. out[i] = ipt[i] * a[i>>2].
// 3 VMEM per float4 (1 cached scalar + nt load + nt store), zero divisions.
// Grid-stride at exactly full occupancy: 2048 blocks * 256 thr = 32 waves/CU.
// ---------------------------------------------------------------------------
__global__ void __launch_bounds__(256)
apply_kernel(const f4_t* __restrict__ ipt,
             const float* __restrict__ amap,
             f4_t* __restrict__ out) {
    const int stride = gridDim.x * 256;
    for (int i = blockIdx.x * 256 + threadIdx.x; i < N4; i += stride) {
        float a = amap[i >> 2];                       // L1/L3-hit (4 lanes share)
        f4_t v  = __builtin_nontemporal_load(ipt + i);
        f4_t o;
        o.x = v.x * a;
        o.y = v.y * a;
        o.z = v.z * a;
        o.w = v.w * a;
        __builtin_nontemporal_store(o, out + i);
    }
}

// ---------------------------------------------------------------------------
// Fallback path (verified previous kernels) if workspace is too small
// ---------------------------------------------------------------------------
__global__ void __launch_bounds__(64)
norms_kernel(const float* __restrict__ s_o,
             const float* __restrict__ t_o,
             float* __restrict__ inv) {
    const int b = blockIdx.x;
    const int lane = threadIdx.x;
    float acc_t = 0.f;
    const float* tr = t_o + b * HEIGHT;
    for (int i = lane; i < HEIGHT; i += 64) {
        float v = tr[i];
        acc_t += v * v;
    }
    float acc_s = 0.f;
    if (lane < WIDTH) {
        float v = s_o[b * WIDTH + lane];
        acc_s = v * v;
    }
    #pragma unroll
    for (int off = 32; off > 0; off >>= 1) {
        acc_t += __shfl_down(acc_t, off, 64);
        acc_s += __shfl_down(acc_s, off, 64);
    }
    if (lane == 0) {
        inv[b]         = 1.0f / sqrtf(fmaxf(acc_t, 1e-12f));
        inv[BATCH + b] = 1.0f / sqrtf(fmaxf(acc_s, 1e-12f));
    }
}

__global__ void __launch_bounds__(256)
scale_kernel(const float* __restrict__ s_o,
             const float* __restrict__ t_o,
             const float4* __restrict__ ipt,
             const float* __restrict__ inv,
             float4* __restrict__ out) {
    const int n4 = N4;
    int i = blockIdx.x * blockDim.x + threadIdx.x;
    if (i >= n4) return;
    int p  = i >> 2;
    int w  = p % WIDTH;
    int bh = p / WIDTH;
    int h  = bh % HEIGHT;
    int b  = bh / HEIGHT;
    float roi = (float)((ROI_MASK >> w) & 1u);
    float a = (t_o[b * HEIGHT + h] * inv[b]) * (s_o[b * WIDTH + w] * inv[BATCH + b]) + roi;
    float4 v = ipt[i];
    float4 o;
    o.x = v.x * a;
    o.y = v.y * a;
    o.z = v.z * a;
    o.w = v.w * a;
    out[i] = o;
}

extern "C" void kernel_launch(void* const* d_in, const int* in_sizes, int n_in,
                              void* d_out, int out_size, void* d_ws, size_t ws_size,
                              hipStream_t stream) {
    const float* s_o = (const float*)d_in[0];  // [1024, 25]
    const float* t_o = (const float*)d_in[1];  // [1024, 300]
    const float* ipt = (const float*)d_in[2];  // [1024, 300, 25, 16]
    float* out = (float*)d_out;

    if (ws_size >= (size_t)NCELL * sizeof(float)) {
        float* amap = (float*)d_ws;            // 30.72 MB
        amap_kernel<<<BATCH, 64, 0, stream>>>(s_o, t_o, amap);
        apply_kernel<<<2048, 256, 0, stream>>>((const f4_t*)ipt, amap, (f4_t*)out);
    } else {
        float* inv = (float*)d_ws;             // 8 KB fallback
        norms_kernel<<<BATCH, 64, 0, stream>>>(s_o, t_o, inv);
        const int blocks = (N4 + 255) / 256;
        scale_kernel<<<blocks, 256, 0, stream>>>(s_o, t_o, (const float4*)ipt, inv,
                                                 (float4*)out);
    }
}

// Round 4
// 748.645 us; speedup vs baseline: 1.0477x; 1.0477x over previous
//
#include <hip/hip_runtime.h>
#include <math.h>

#define HEIGHT 300
#define WIDTH  25
#define CH     16
#define BATCH  1024
// bits set at w = 3, 8, 12, 14, 17, 19
#define ROI_MASK 0x000A5108u

#define NCELL (BATCH * HEIGHT * WIDTH)   // 7,680,000 cells
#define N4    (NCELL * (CH / 4))         // 30,720,000 float4s

// Native clang ext_vector: required for __builtin_nontemporal_load/store
// (HIP's float4 is a class type and is rejected by the builtin).
typedef float f4_t __attribute__((ext_vector_type(4)));

// ---------------------------------------------------------------------------
// Kernel 1: per-batch inverse L2 norms. One wave (64 lanes) per batch row.
// inv[0..1023]    = 1/sqrt(max(sum t_o[b]^2, 1e-12))
// inv[1024..2047] = 1/sqrt(max(sum s_o[b]^2, 1e-12))
// ---------------------------------------------------------------------------
__global__ void __launch_bounds__(64)
norms_kernel(const float* __restrict__ s_o,
             const float* __restrict__ t_o,
             float* __restrict__ inv) {
    const int b = blockIdx.x;
    const int lane = threadIdx.x;

    float acc_t = 0.f;
    const float* tr = t_o + b * HEIGHT;
    for (int i = lane; i < HEIGHT; i += 64) {
        float v = tr[i];
        acc_t += v * v;
    }
    float acc_s = 0.f;
    if (lane < WIDTH) {
        float v = s_o[b * WIDTH + lane];
        acc_s = v * v;
    }
    #pragma unroll
    for (int off = 32; off > 0; off >>= 1) {
        acc_t += __shfl_down(acc_t, off, 64);
        acc_s += __shfl_down(acc_s, off, 64);
    }
    if (lane == 0) {
        inv[b]         = 1.0f / sqrtf(fmaxf(acc_t, 1e-12f));
        inv[BATCH + b] = 1.0f / sqrtf(fmaxf(acc_s, 1e-12f));
    }
}

// ---------------------------------------------------------------------------
// Kernel 2: out[b,h,w,c] = (t̂[b,h] * ŝ[b,w] + roi[w]) * ipt[b,h,w,c]
// One float4 (4 channels) per thread, flat grid, fully coalesced 1 KB/wave
// per VMEM instruction. Scalar a-factors are L1/L2-hits (4 lanes share).
// Nontemporal on the 983 MB one-shot stream keeps it out of L2's way.
// ---------------------------------------------------------------------------
__global__ void __launch_bounds__(256)
scale_kernel(const float* __restrict__ s_o,
             const float* __restrict__ t_o,
             const f4_t* __restrict__ ipt,
             const float* __restrict__ inv,
             f4_t* __restrict__ out) {
    int i = blockIdx.x * 256 + threadIdx.x;
    if (i >= N4) return;

    int p  = i >> 2;          // (b,h,w) flat cell index
    int w  = p % WIDTH;       // compiler emits magic-mul
    int bh = p / WIDTH;
    int h  = bh % HEIGHT;
    int b  = bh / HEIGHT;

    float roi = (float)((ROI_MASK >> w) & 1u);
    float a = (t_o[b * HEIGHT + h] * inv[b]) * (s_o[b * WIDTH + w] * inv[BATCH + b]) + roi;

    f4_t v = __builtin_nontemporal_load(ipt + i);
    f4_t o;
    o.x = v.x * a;
    o.y = v.y * a;
    o.z = v.z * a;
    o.w = v.w * a;
    __builtin_nontemporal_store(o, out + i);
}

extern "C" void kernel_launch(void* const* d_in, const int* in_sizes, int n_in,
                              void* d_out, int out_size, void* d_ws, size_t ws_size,
                              hipStream_t stream) {
    const float* s_o = (const float*)d_in[0];  // [1024, 25]
    const float* t_o = (const float*)d_in[1];  // [1024, 300]
    const float* ipt = (const float*)d_in[2];  // [1024, 300, 25, 16]
    float* out = (float*)d_out;
    float* inv = (float*)d_ws;                 // 2048 floats = 8 KB

    norms_kernel<<<BATCH, 64, 0, stream>>>(s_o, t_o, inv);

    const int blocks = (N4 + 255) / 256;       // 120,000 blocks
    scale_kernel<<<blocks, 256, 0, stream>>>(s_o, t_o, (const f4_t*)ipt, inv,
                                             (f4_t*)out);
}